// Round 3
// baseline (47.375 us; speedup 1.0000x reference)
//
#include <hip/hip_runtime.h>

#define DD 128
#define HH 256
#define WW 256
#define OD 127
#define NCHUNK 16
#define DCHUNK 8
#define SLICE_F (HH*WW)
#define NBIN 64

struct Raw { float4 p0, p1; uint4 t0, t1; };
struct Sl  { float uu2[4]; float vv2[4]; int nib[4]; };

__device__ __forceinline__ void load_raw(const float* __restrict__ pB,
                                         const float* __restrict__ tB,
                                         int d, Raw& R)
{
    const float4* p = (const float4*)(pB + ((size_t)d << 16));
    const uint4*  t = (const uint4*) (tB + ((size_t)d << 16));
    R.p0 = p[0]; R.p1 = p[WW/4];
    R.t0 = t[0]; R.t1 = t[WW/4];
}

__device__ __forceinline__ void make_sl(const Raw& R, Sl& S)
{
    // u = e^x; sigma = u/(1+u); 1-sigma = 1/(1+u)
    float u00=__expf(R.p0.x), u01=__expf(R.p0.y), u02=__expf(R.p0.z), u03=__expf(R.p0.w);
    float u10=__expf(R.p1.x), u11=__expf(R.p1.y), u12=__expf(R.p1.z), u13=__expf(R.p1.w);
    float un0=__shfl_down(u00,1), un1=__shfl_down(u10,1);
    float w0=u00*u10, w1=u01*u11, w2=u02*u12, w3=u03*u13, w4=un0*un1;
    float q0=(1.f+u00)*(1.f+u10), q1=(1.f+u01)*(1.f+u11), q2=(1.f+u02)*(1.f+u12),
          q3=(1.f+u03)*(1.f+u13), q4=(1.f+un0)*(1.f+un1);
    S.uu2[0]=w0*w1; S.uu2[1]=w1*w2; S.uu2[2]=w2*w3; S.uu2[3]=w3*w4;
    S.vv2[0]=q0*q1; S.vv2[1]=q1*q2; S.vv2[2]=q2*q3; S.vv2[3]=q3*q4;
    // targets: exact bit extraction (t is 0.0f or 1.0f -> 0x0 or 0x3F800000)
    int b00=R.t0.x>>29, b01=R.t0.y>>29, b02=R.t0.z>>29, b03=R.t0.w>>29;
    int b10=R.t1.x>>29, b11=R.t1.y>>29, b12=R.t1.z>>29, b13=R.t1.w>>29;
    int pk = b00 | (b10<<1);
    int pn = __shfl_down(pk,1);
    // nibble bit k = kh*2+kw
    S.nib[0] = b00 | (b01<<1) | (b10<<2) | (b11<<3);
    S.nib[1] = b01 | (b02<<1) | (b11<<2) | (b12<<3);
    S.nib[2] = b02 | (b03<<1) | (b12<<2) | (b13<<3);
    S.nib[3] = b03 | ((pn&1)<<1) | (b13<<2) | ((pn>>1)<<3);
}

__device__ __forceinline__ void do_cubes(const Sl& P, const Sl& C,
        float valid3, int mask63,
        float& aFG, float& aFG255, float& aBG, float& aBG0, float& aSFA,
        int& c255, int& c0i, int& cMN)
{
    #pragma unroll
    for (int j = 0; j < 4; ++j) {
        float E = P.uu2[j]*C.uu2[j];
        float Q = P.vv2[j]*C.vv2[j];
        float r = __builtin_amdgcn_rcpf(Q);
        if (j == 3) r *= valid3;          // mask cube at w=255 (lane 63)
        float fg = E*r;
        float bg = r;
        int code = P.nib[j] | (C.nib[j] << 4);
        int pop  = __popc(code);
        int mn   = min(pop, 8 - pop);     // area*2 (0.5 folded into final)
        int i255 = (code == 255) ? -1 : 0;
        int i0   = (code == 0)   ? -1 : 0;
        if (j == 3) { mn &= mask63; i255 &= mask63; i0 &= mask63; }
        float mf = (float)mn;
        aFG += fg;
        aFG255 += __int_as_float(__float_as_int(fg) & i255);
        aBG += bg;
        aBG0 += __int_as_float(__float_as_int(bg) & i0);
        aSFA = fmaf(fg + bg, mf, aSFA);
        c255 -= i255; c0i -= i0; cMN += mn;
    }
}

// ws layout: [NBIN][2 batches][8 sums]
// 0 sum(fg) 1 sum(fg*gtfg) 2 cnt(gtfg) 3 sum(bg) 4 sum(bg*gtbg) 5 cnt(gtbg)
// 6 sum((fg+bg)*2a) 7 sum(2a)
__global__ __launch_bounds__(256)
void loss_main(const float* __restrict__ preds,
               const float* __restrict__ targets,
               float* __restrict__ ws)
{
    const int lane = threadIdx.x & 63;
    const int wv   = threadIdx.x >> 6;
    const int h    = blockIdx.x * 4 + wv;
    if (h >= HH - 1) return;               // no barriers anywhere
    const int b    = blockIdx.z;
    const int d0   = blockIdx.y * DCHUNK;
    const int dend = min(d0 + DCHUNK, OD);

    const size_t colBase = (size_t)b * DD * SLICE_F + (size_t)h * WW + (size_t)(lane << 2);
    const float* pB = preds + colBase;
    const float* tB = targets + colBase;
    const float valid3 = (lane == 63) ? 0.f : 1.f;
    const int   mask63 = (lane == 63) ? 0 : -1;

    float aFG=0.f, aFG255=0.f, aBG=0.f, aBG0=0.f, aSFA=0.f;
    int c255=0, c0i=0, cMN=0;

    Raw R0, R1; Sl A, B;
    load_raw(pB, tB, d0,     R0);
    load_raw(pB, tB, d0 + 1, R1);
    make_sl(R0, A);
    load_raw(pB, tB, min(d0 + 2, DD - 1), R0);

    int d = d0;
    for (; d + 2 <= dend; d += 2) {
        make_sl(R1, B);                                   // consumes slice d+1
        load_raw(pB, tB, min(d + 3, DD - 1), R1);         // prefetch, ~1 iter ahead
        do_cubes(A, B, valid3, mask63, aFG, aFG255, aBG, aBG0, aSFA, c255, c0i, cMN);
        make_sl(R0, A);                                   // consumes slice d+2
        load_raw(pB, tB, min(d + 4, DD - 1), R0);
        do_cubes(B, A, valid3, mask63, aFG, aFG255, aBG, aBG0, aSFA, c255, c0i, cMN);
    }
    if (d < dend) {
        make_sl(R1, B);
        do_cubes(A, B, valid3, mask63, aFG, aFG255, aBG, aBG0, aSFA, c255, c0i, cMN);
    }

    float acc[8] = {aFG, aFG255, (float)c255, aBG, aBG0, (float)c0i, aSFA, (float)cMN};
    #pragma unroll
    for (int i = 0; i < 8; ++i) {
        float v = acc[i];
        #pragma unroll
        for (int off = 32; off > 0; off >>= 1) v += __shfl_xor(v, off);
        acc[i] = v;
    }
    float mine = acc[0];
    mine = (lane == 1) ? acc[1] : mine;
    mine = (lane == 2) ? acc[2] : mine;
    mine = (lane == 3) ? acc[3] : mine;
    mine = (lane == 4) ? acc[4] : mine;
    mine = (lane == 5) ? acc[5] : mine;
    mine = (lane == 6) ? acc[6] : mine;
    mine = (lane == 7) ? acc[7] : mine;
    if (lane < 8)
        atomicAdd(&ws[((blockIdx.x & (NBIN - 1)) * 2 + b) * 8 + lane], mine);
}

__global__ void loss_final(const float* __restrict__ ws, float* __restrict__ out)
{
    __shared__ float s[16];
    const int t = threadIdx.x;
    if (t < 16) {
        float v = 0.f;
        #pragma unroll 4
        for (int x = 0; x < NBIN; ++x) v += ws[x * 16 + t];
        s[t] = v;
    }
    __syncthreads();
    if (t == 0) {
        const float eps = 1e-5f;
        float dice = 0.f;
        #pragma unroll
        for (int b = 0; b < 2; ++b) {
            const float* q = s + b * 8;
            float fg_dice = (2.f*q[1] + eps) / (q[0] + q[2] + eps);
            float bg_dice = (2.f*q[4] + eps) / (q[3] + q[5] + eps);
            float q6 = 0.5f * q[6];                 // restore the 0.5*min(pop,8-pop)
            float q7 = 0.5f * q[7];
            float ss = q7 - q6;                     // sum(surf*area)
            float sf_dice = (2.f*ss + eps) / (ss + q7 + eps);
            dice += fg_dice + bg_dice + sf_dice;
        }
        out[0] = 1.f - dice * (1.f/6.f);
    }
}

extern "C" void kernel_launch(void* const* d_in, const int* in_sizes, int n_in,
                              void* d_out, int out_size, void* d_ws, size_t ws_size,
                              hipStream_t stream)
{
    const float* preds   = (const float*)d_in[0];
    const float* targets = (const float*)d_in[1];
    // d_in[2] power / d_in[3] kernel / d_in[4] area are analytic -- baked in
    float* ws = (float*)d_ws;

    hipMemsetAsync(ws, 0, NBIN * 16 * sizeof(float), stream);

    dim3 grid(64, NCHUNK, 2);   // 2048 blocks
    loss_main<<<grid, 256, 0, stream>>>(preds, targets, ws);
    loss_final<<<1, 64, 0, stream>>>(ws, (float*)d_out);
}